// Round 4
// baseline (315.603 us; speedup 1.0000x reference)
//
#include <hip/hip_runtime.h>

// Depthwise transposed conv K=3, S=2, SAME. x:(8,128,128,128) NHWC fp32,
// w:(3,3,1,128) HWIO fp32 -> out:(8,256,256,128) fp32.
//
// ROUND-4 CHANGE: fill-like linear temporal write order + sustained per-wave
// streaming. Evidence: kernel stuck at 147-164us (~2.2 TB/s) across 4
// structures varying TLP (16..512 waves/CU), ILP, instruction count (4x),
// and store type -- invariant is bytes, i.e. a bandwidth ceiling, but the
// harness's own fillBuffer does 6.5 TB/s on the same output arena. Remaining
// untested axis vs fill/copy: concurrent waves scattered over the whole
// 256 MiB (512B islands) vs one dense linearly-advancing window, and
// one-shot dependent bursts vs steady multi-step streams.
//
// Structure: task = (n, y, seg): one block produces the contiguous 128 KiB
// output run [rows 2y..2y+1] x [cols 128*seg .. 128*seg+127] x 128ch,
// sweeping left->right in 8 steps of 16 KiB. Per step a wave stores 2
// contiguous 2 KiB runs; steps advance linearly; consecutive blocks own
// adjacent 128 KiB runs. Each wave runs an 8-step load->compute->store
// pipeline with step-independent addresses (compiler overlaps steps).
//
// Thread: c4 = tid&31 (channel float4, 512B contiguous), tcol = tid>>5
// (input column within step). Step k: t = 64*seg + 8k + tcol.
// Halo loads (t-1) hit lines already being loaded by the neighboring lane
// group (L1-served) -> no extra HBM traffic.
//
// out[2y+0, 2t+0] = w00*x[y,t] + w02*x[y,t-1] + w20*x[y-1,t] + w22*x[y-1,t-1]
// out[2y+0, 2t+1] = w01*x[y,t] + w21*x[y-1,t]
// out[2y+1, 2t+0] = w10*x[y,t] + w12*x[y,t-1]
// out[2y+1, 2t+1] = w11*x[y,t]

typedef float v4f __attribute__((ext_vector_type(4)));

__global__ __launch_bounds__(256, 4) void upsample_tconv_kernel(
    const float* __restrict__ x, const float* __restrict__ w,
    float* __restrict__ out)
{
    // grid: 8 * 128 * 2 = 2048 blocks; block = one 128 KiB output run
    int b = blockIdx.x;
    int seg = b & 1;            // output column half
    int y   = (b >> 1) & 127;   // input row
    int n   = b >> 8;           // batch

    int tid  = threadIdx.x;
    int c4   = tid & 31;        // float4 chunk of 128 channels
    int tcol = tid >> 5;        // input column slot within a step (0..7)

    // All 9 taps. w[j][i][c] -> (j*3+i)*32 + c4
    const v4f* wv = (const v4f*)w;
    v4f w00 = wv[0 * 32 + c4];
    v4f w01 = wv[1 * 32 + c4];
    v4f w02 = wv[2 * 32 + c4];
    v4f w10 = wv[3 * 32 + c4];
    v4f w11 = wv[4 * 32 + c4];
    v4f w12 = wv[5 * 32 + c4];
    v4f w20 = wv[6 * 32 + c4];
    v4f w21 = wv[7 * 32 + c4];
    v4f w22 = wv[8 * 32 + c4];

    const v4f zero = (v4f)(0.f);
    const v4f* xv = (const v4f*)x;
    v4f* ov = (v4f*)out;

    bool has_up = (y > 0);                               // wave-uniform
    int rowb  = ((n * 128 + y) * 128) * 32 + c4;         // x[y, 0]
    int obrow = ((n * 256 + (y << 1)) * 256) * 32 + c4;  // out[2y, 0]
    int tb = (seg << 6) + tcol;

    #pragma unroll
    for (int k = 0; k < 8; ++k) {
        int t = tb + (k << 3);
        int base = rowb + t * 32;
        v4f xa  = xv[base];                                        // x[y,   t]
        v4f xpa = (t > 0) ? xv[base - 32] : zero;                  // x[y,   t-1]
        v4f xc  = has_up ? xv[base - 128 * 32] : zero;             // x[y-1, t]
        v4f xpc = (has_up && t > 0) ? xv[base - 128 * 32 - 32] : zero;

        v4f o_ee = w00 * xa + w02 * xpa + w20 * xc + w22 * xpc;    // out[2y,  2t]
        v4f o_eo = w01 * xa + w21 * xc;                            // out[2y,  2t+1]
        v4f o_oe = w10 * xa + w12 * xpa;                           // out[2y+1,2t]
        v4f o_oo = w11 * xa;                                       // out[2y+1,2t+1]

        int ob = obrow + (t << 1) * 32;
        __builtin_nontemporal_store(o_ee, &ov[ob]);
        __builtin_nontemporal_store(o_eo, &ov[ob + 32]);
        __builtin_nontemporal_store(o_oe, &ov[ob + 256 * 32]);
        __builtin_nontemporal_store(o_oo, &ov[ob + 256 * 32 + 32]);
    }
}

extern "C" void kernel_launch(void* const* d_in, const int* in_sizes, int n_in,
                              void* d_out, int out_size, void* d_ws, size_t ws_size,
                              hipStream_t stream) {
    const float* x = (const float*)d_in[0];
    const float* w = (const float*)d_in[1];
    float* out = (float*)d_out;

    // 2048 blocks x 256 threads
    upsample_tconv_kernel<<<dim3(2048), dim3(256), 0, stream>>>(x, w, out);
}